// Round 15
// baseline (300.688 us; speedup 1.0000x reference)
//
#include <hip/hip_runtime.h>
#include <stdint.h>

// Problem constants
#define S_LEN 2048
#define DIM_   4096
#define NH_    32
#define NKV_   8
#define HD_    128
#define QK_SCALE 0.08838834764831845f   // 1/sqrt(128)

typedef __attribute__((ext_vector_type(8)))  short  s16x8;   // 8 bf16 (4 VGPRs) MFMA frag
typedef __attribute__((ext_vector_type(4)))  float  f32x4;   // 16x16 MFMA accum
typedef __attribute__((ext_vector_type(16))) float  f32x16;  // 32x32 MFMA accum
typedef __attribute__((ext_vector_type(8))) unsigned short u16x8;
typedef __attribute__((ext_vector_type(4))) unsigned short u16x4;

union frag_u { s16x8 f; uint32_t w[4]; };

__device__ __forceinline__ unsigned short f2bf(float f) {
  union { float f; uint32_t u; } v; v.f = f;
  return (unsigned short)((v.u + 0x7fffu + ((v.u >> 16) & 1u)) >> 16);   // RNE
}

__device__ __forceinline__ float bf2f(unsigned short u) {
  union { uint32_t u; float f; } v; v.u = (uint32_t)u << 16;
  return v.f;
}

__device__ __forceinline__ uint32_t cvt_pk_bf16(float lo, float hi2) {
  uint32_t r;
  asm volatile("v_cvt_pk_bf16_f32 %0, %1, %2" : "=v"(r) : "v"(lo), "v"(hi2));
  return r;
}

// async global->LDS, 16B per lane. LDS dest is wave-uniform base + lane*16.
__device__ __forceinline__ void async_cp16(const void* g, void* l) {
  __builtin_amdgcn_global_load_lds(
      (const __attribute__((address_space(1))) unsigned int*)g,
      (__attribute__((address_space(3))) unsigned int*)l, 16, 0, 0);
}

#define WAITV(n) asm volatile("s_waitcnt vmcnt(" #n ")" ::: "memory")

// ------------- fused cast fp32 -> bf16 for all 5 inputs -------------
__global__ __launch_bounds__(256) void cast_all(
    const float* __restrict__ x,  const float* __restrict__ wq,
    const float* __restrict__ wk, const float* __restrict__ wv,
    const float* __restrict__ wo, unsigned short* __restrict__ xb,
    unsigned short* __restrict__ wqkvb, unsigned short* __restrict__ wob) {
  const int i = blockIdx.x * 256 + threadIdx.x;
  const float* src; unsigned short* dst; int off;
  if (i < 2097152)      { src = x;  dst = xb;               off = i; }
  else if (i < 6291456) { src = wq; dst = wqkvb;            off = i - 2097152; }
  else if (i < 7340032) { src = wk; dst = wqkvb + 16777216; off = i - 6291456; }
  else if (i < 8388608) { src = wv; dst = wqkvb + 20971520; off = i - 7340032; }
  else                  { src = wo; dst = wob;              off = i - 8388608; }
  const float4 v = ((const float4*)src)[off];
  u16x4 o; o[0] = f2bf(v.x); o[1] = f2bf(v.y); o[2] = f2bf(v.z); o[3] = f2bf(v.w);
  ((u16x4*)dst)[off] = o;
}

// == 128 x NTILE_N 2-phase GEMM, 4 waves x (64 x NTILE_N/2), rotate-slot ====
// R12/R13 proven skeleton + ONE overlap change (R15): LDBK1 (same-tile kk=1
// B-fragments, buf P B-region) issues in p0 right after the lgkm drain, so
// its ds_reads fly UNDER MFK(0). Safety: (a) tile J's B resident since group
// J-1's gate (only A(J+1) left in flight there); (b) window writers to buf P
// = STGA -> A region only (disjoint); STGB -> P^1; (c) fbk1 regs distinct
// from fbk0; (d) MFK(1) guarded by fresh lgkmcnt(0)+sched_barrier (rule #18).
// The R8/R9 races are explained and avoided: A(J+1) is NOT proven resident
// until the END-of-group gate, so no cross-tile read-ahead is attempted.
template <int NT, int NTILE_N, int NCF, int NBCH, int BF16OUT>
__global__ __launch_bounds__(256, 2) void gemmF(
    const unsigned short* __restrict__ A, const unsigned short* __restrict__ B,
    void* __restrict__ C, int ldc) {
  constexpr int BUFB = 16384 + NTILE_N * 128;   // bytes per buffer
  __shared__ unsigned char lds[2 * BUFB];

  const int bid = blockIdx.x;
  const int idx = (bid & 7) * 64 + (bid >> 3);   // XCD-contiguous
  const int m = idx & 15, n = idx >> 4;
  const int m0 = m * 128, n0 = n * NTILE_N;

  const int tid = threadIdx.x;
  const int wave = tid >> 6, lane = tid & 63;
  const int wm = wave >> 1, wn = wave & 1;
  const int fr = lane & 15, g = lane >> 4;

  int offA[4][2], offB[NCF][2];
#pragma unroll
  for (int rf = 0; rf < 4; ++rf)
#pragma unroll
    for (int kk = 0; kk < 2; ++kk)
      offA[rf][kk] = wm * 8192 + (rf * 16 + fr) * 128 + (((kk * 4 + g + fr) & 7) << 4);
#pragma unroll
  for (int cf = 0; cf < NCF; ++cf)
#pragma unroll
    for (int kk = 0; kk < 2; ++kk)
      offB[cf][kk] = (wn * NCF * 16 + cf * 16 + fr) * 128 + (((kk * 4 + g + fr) & 7) << 4);

  const int srk = (((tid & 7) - (tid >> 3)) & 7) * 8;
  uint32_t aoff[2][2];
  uint32_t boff[NBCH];
#pragma unroll
  for (int h = 0; h < 2; ++h)
#pragma unroll
    for (int i = 0; i < 2; ++i)
      aoff[h][i] = (uint32_t)((m0 + h * 64 + i * 32 + (tid >> 3)) * 4096 + srk);
#pragma unroll
  for (int i = 0; i < NBCH; ++i)
    boff[i] = (uint32_t)((n0 + i * 32 + (tid >> 3)) * 4096 + srk);

  f32x4 acc[4][NCF] = {};
  s16x8 fa[4][2], fbk0[NCF], fbk1[NCF];

#define STGA(T, BUF)                                                          \
  { _Pragma("unroll") for (int h_ = 0; h_ < 2; ++h_)                          \
      _Pragma("unroll") for (int i_ = 0; i_ < 2; ++i_)                        \
        async_cp16(A + aoff[h_][i_] + (size_t)(T) * 64,                       \
                   (char*)lds + (BUF) * BUFB + h_ * 8192 + i_ * 4096 + tid * 16); }
#define STGB(T, BUF)                                                          \
  { _Pragma("unroll") for (int i_ = 0; i_ < NBCH; ++i_)                       \
      async_cp16(B + boff[i_] + (size_t)(T) * 64,                             \
                 (char*)lds + (BUF) * BUFB + 16384 + i_ * 4096 + tid * 16); }
#define LDA2(P)                                                               \
  { _Pragma("unroll") for (int rf = 0; rf < 4; ++rf)                          \
      _Pragma("unroll") for (int kk = 0; kk < 2; ++kk)                        \
        fa[rf][kk] = *(const s16x8*)((char*)lds + (P) * BUFB + offA[rf][kk]); }
#define LDBK0(P)                                                              \
  { _Pragma("unroll") for (int cf = 0; cf < NCF; ++cf)                        \
      fbk0[cf] = *(const s16x8*)((char*)lds + (P) * BUFB + 16384 + offB[cf][0]); }
#define LDBK1(P)                                                              \
  { _Pragma("unroll") for (int cf = 0; cf < NCF; ++cf)                        \
      fbk1[cf] = *(const s16x8*)((char*)lds + (P) * BUFB + 16384 + offB[cf][1]); }
#define SB __builtin_amdgcn_sched_barrier(0)
#define BARLG()                                                               \
  __builtin_amdgcn_s_barrier();                                               \
  asm volatile("s_waitcnt lgkmcnt(0)" ::: "memory");                          \
  SB;
#define MFK(KK, FBK)                                                          \
  __builtin_amdgcn_s_setprio(1);                                              \
  { _Pragma("unroll") for (int rf = 0; rf < 4; ++rf)                          \
      _Pragma("unroll") for (int cf = 0; cf < NCF; ++cf)                      \
        acc[rf][cf] = __builtin_amdgcn_mfma_f32_16x16x32_bf16(                \
            fa[rf][KK], FBK[cf], acc[rf][cf], 0, 0, 0); }                     \
  __builtin_amdgcn_s_setprio(0);

#define GROUPF(J, P, DO1, DO2, GATE)                                          \
  {                                                                           \
    LDA2(P); LDBK0(P);                                                        \
    if (DO1) { STGB((J) + 1, (P) ^ 1); }                                      \
    BARLG();                         /* all p0 reads resident */              \
    LDBK1(P);                        /* kk=1 B reads fly under MFK(0) */      \
    SB;                                                                       \
    MFK(0, fbk0);                                                             \
    __builtin_amdgcn_s_barrier();    /* mid-barrier (A-region WAR fence) */   \
    if (DO2) { STGA((J) + 2, P); }                                            \
    asm volatile("s_waitcnt lgkmcnt(0)" ::: "memory");   /* drain fbk1 */     \
    SB;                                                                       \
    MFK(1, fbk1);                                                             \
    GATE;                                                                     \
    __builtin_amdgcn_s_barrier();                                             \
  }

  STGA(0, 0); STGB(0, 0); STGA(1, 1);
  WAITV(4);
  __builtin_amdgcn_s_barrier();

  for (int j = 0; j + 3 < NT; j += 2) {
    GROUPF(j, 0, true, true, WAITV(4));
    GROUPF(j + 1, 1, true, true, WAITV(4));
  }
  GROUPF(NT - 2, 0, true, false, WAITV(0));
  GROUPF(NT - 1, 1, false, false, );

#pragma unroll
  for (int rf = 0; rf < 4; ++rf)
#pragma unroll
    for (int cf = 0; cf < NCF; ++cf) {
      const size_t rbase = (size_t)(m0 + wm * 64 + rf * 16 + g * 4) * ldc
                         + (n0 + wn * NCF * 16 + cf * 16 + fr);
      if constexpr (BF16OUT) {
        unsigned short* cp = (unsigned short*)C + rbase;
#pragma unroll
        for (int r = 0; r < 4; ++r) cp[(size_t)r * ldc] = f2bf(acc[rf][cf][r]);
      } else {
        float* cp = (float*)C + rbase;
#pragma unroll
        for (int r = 0; r < 4; ++r) cp[(size_t)r * ldc] = acc[rf][cf][r];
      }
    }
#undef STGA
#undef STGB
#undef LDA2
#undef LDBK0
#undef LDBK1
#undef SB
#undef BARLG
#undef MFK
#undef GROUPF
}

// ---- fused RoPE on Q and K: bf16 xqkv -> qb/kb (+fp32 cache_k) -----
__global__ __launch_bounds__(256) void rope_qk_kern(
    const unsigned short* __restrict__ xqkv, const float* __restrict__ cos_f,
    const float* __restrict__ sin_f, unsigned short* __restrict__ qb,
    float* __restrict__ ck, unsigned short* __restrict__ kb) {
  const int gid = blockIdx.x * 256 + threadIdx.x;   // 2048*640 threads
  const int s = gid / 640;
  const int e0 = (gid - s * 640) * 8;
  const int i0 = (e0 & 127) >> 1;
  const float4 c  = *(const float4*)(cos_f + s * 64 + i0);
  const float4 sn = *(const float4*)(sin_f + s * 64 + i0);
  const u16x8 uv = *(const u16x8*)(xqkv + (size_t)s * 6144 + e0);
  float f[8];
#pragma unroll
  for (int j = 0; j < 8; ++j) f[j] = bf2f(uv[j]);
  const float r0 = f[0] * c.x - f[1] * sn.x, r1 = f[0] * sn.x + f[1] * c.x;
  const float r2 = f[2] * c.y - f[3] * sn.y, r3 = f[2] * sn.y + f[3] * c.y;
  const float r4 = f[4] * c.z - f[5] * sn.z, r5 = f[4] * sn.z + f[5] * c.z;
  const float r6 = f[6] * c.w - f[7] * sn.w, r7 = f[6] * sn.w + f[7] * c.w;
  if (e0 < 4096) {
    u16x8 o;
    o[0] = f2bf(r0 * QK_SCALE); o[1] = f2bf(r1 * QK_SCALE);
    o[2] = f2bf(r2 * QK_SCALE); o[3] = f2bf(r3 * QK_SCALE);
    o[4] = f2bf(r4 * QK_SCALE); o[5] = f2bf(r5 * QK_SCALE);
    o[6] = f2bf(r6 * QK_SCALE); o[7] = f2bf(r7 * QK_SCALE);
    *(u16x8*)(qb + (size_t)s * 4096 + e0) = o;
  } else {
    const int col = e0 - 4096;
    float4 o1; o1.x = r0; o1.y = r1; o1.z = r2; o1.w = r3;
    float4 o2; o2.x = r4; o2.y = r5; o2.z = r6; o2.w = r7;
    *(float4*)(ck + (size_t)s * 1024 + col) = o1;
    *(float4*)(ck + (size_t)s * 1024 + col + 4) = o2;
    u16x8 o;
    o[0] = f2bf(r0); o[1] = f2bf(r1); o[2] = f2bf(r2); o[3] = f2bf(r3);
    o[4] = f2bf(r4); o[5] = f2bf(r5); o[6] = f2bf(r6); o[7] = f2bf(r7);
    *(u16x8*)(kb + (size_t)s * 1024 + col) = o;
  }
}

// -- V: bf16 xqkv -> fp32 cache out (coalesced) + bf16 V^T [NKV*HD][S] --
__global__ __launch_bounds__(256) void vtrans_kern(
    const unsigned short* __restrict__ xqkv, float* __restrict__ cv,
    unsigned short* __restrict__ vtb) {
  __shared__ float tile[64][65];
  const int st = blockIdx.x * 64;
  const int ct = blockIdx.y * 64;
  const int tid = threadIdx.x;
#pragma unroll
  for (int j = 0; j < 16; ++j) {
    const int lin = tid + j * 256;
    const int si = lin >> 6, ci = lin & 63;
    const float v = bf2f(xqkv[(size_t)(st + si) * 6144 + 5120 + ct + ci]);
    cv[(size_t)(st + si) * 1024 + ct + ci] = v;
    tile[si][ci] = v;
  }
  __syncthreads();
#pragma unroll
  for (int j = 0; j < 16; ++j) {
    const int lin = tid + j * 256;
    const int co = lin >> 6, so = lin & 63;
    vtb[(size_t)(ct + co) * 2048 + st + so] = f2bf(tile[so][co]);
  }
}

// ---------------- flash attention v3 (unchanged from R14) -----------
__global__ __launch_bounds__(256, 2) void attn_fwd3(
    const unsigned short* __restrict__ qb, const unsigned short* __restrict__ kb,
    const unsigned short* __restrict__ vtb, unsigned short* __restrict__ ob) {
  __shared__ unsigned short Ks[2][64 * 128];
  __shared__ unsigned short Vs[2][128 * 64];
  const int bid = blockIdx.x;
  const int xcd = bid & 7;
  const int rem = bid >> 3;
  const int h   = xcd * 4 + (rem & 3);
  const int slot = rem >> 2;
  const int hkv = h >> 2;
  const int g = (slot & 1) ? (15 - (slot >> 1)) : (slot >> 1);
  const int qtile = (h < 16) ? g : (15 - g);
  const int q0 = qtile * 128;
  const int tid = threadIdx.x, wave = tid >> 6, lane = tid & 63;
  const int col = lane & 31;
  const int hi  = lane >> 5;
  const int q0w = q0 + wave * 32;
  const int nt = (q0 >> 6) + 2;

  s16x8 qf[8];
  {
    const unsigned short* qrow = qb + (size_t)(q0w + col) * 4096 + h * 128 + hi * 8;
#pragma unroll
    for (int ks = 0; ks < 8; ++ks) qf[ks] = *(const s16x8*)(qrow + ks * 16);
  }

  f32x16 oacc[4] = {};
  float m_s = -3e30f, l_s = 0.0f;

#define STAGE_K(KT, B)                                                        \
  {                                                                           \
    const unsigned short* src = kb + (size_t)((KT) * 64) * 1024 + hkv * 128;  \
    _Pragma("unroll")                                                         \
    for (int i_ = 0; i_ < 4; ++i_) {                                          \
      const int c_ = wave * 4 + i_;                                           \
      const int row_ = c_ * 4 + (lane >> 4);                                  \
      const int cb_ = ((lane & 15) * 16) ^ ((row_ & 7) << 4);                 \
      async_cp16(src + (size_t)row_ * 1024 + (cb_ >> 1), (char*)Ks[B] + c_ * 1024); \
    }                                                                         \
  }
#define STAGE_V(KT, B)                                                        \
  {                                                                           \
    const unsigned short* src = vtb + (size_t)hkv * (128 * 2048) + (KT) * 64; \
    _Pragma("unroll")                                                         \
    for (int i_ = 0; i_ < 4; ++i_) {                                          \
      const int c_ = wave * 4 + i_;                                           \
      const int row_ = c_ * 8 + (lane >> 3);                                  \
      const int cb_ = ((lane & 7) * 16) ^ ((row_ & 7) << 4);                  \
      async_cp16(src + (size_t)row_ * 2048 + (cb_ >> 1), (char*)Vs[B] + c_ * 1024); \
    }                                                                         \
  }

  STAGE_K(0, 0); STAGE_V(0, 0);
  __syncthreads();

  for (int kt = 0; kt < nt; ++kt) {
    const int kv0 = kt * 64;
    const int cur = kt & 1;
    if (kt + 1 < nt) { STAGE_K(kt + 1, cur ^ 1); STAGE_V(kt + 1, cur ^ 1); }

    if (kv0 < q0w + 32) {
      f32x16 s0 = {}, s1 = {};
#pragma unroll
      for (int ks = 0; ks < 8; ++ks) {
        const int gcb = 32 * ks + 16 * hi;
        const int sw = (col & 7) << 4;
        const s16x8 k0 = *(const s16x8*)((const char*)Ks[cur] + col * 256 + (gcb ^ sw));
        const s16x8 k1 = *(const s16x8*)((const char*)Ks[cur] + (32 + col) * 256 + (gcb ^ sw));
        s0 = __builtin_amdgcn_mfma_f32_32x32x16_bf16(k0, qf[ks], s0, 0, 0, 0);
        s1 = __builtin_amdgcn_mfma_f32_32x32x16_bf16(k1, qf[ks], s1, 0, 0, 0);
      }

      const int qg = q0w + col;
      if (kv0 + 63 > q0w) {
#pragma unroll
        for (int r = 0; r < 16; ++r) {
          const int kvl = (r & 3) + 8 * (r >> 2) + 4 * hi;
          if (kv0 + kvl > qg)      s0[r] = -3e30f;
          if (kv0 + 32 + kvl > qg) s1[r] = -3e30f;
        }
      }

      float mxl = s0[0];
#pragma unroll
      for (int r = 1; r < 16; ++r) mxl = fmaxf(mxl, s0[r]);
#pragma unroll
      for (int r = 0; r < 16; ++r) mxl = fmaxf(mxl, s1[r]);
      const float mxf = fmaxf(mxl, __shfl_xor(mxl, 32));
      if (__any(mxf > m_s + 8.0f)) {
        const float mn = fmaxf(m_s, mxf);
        const float scl = __expf(m_s - mn);
        m_s = mn;
        l_s *= scl;
#pragma unroll
        for (int r = 0; r < 16; ++r) {
          const int qq = (r & 3) + 8 * (r >> 2) + 4 * hi;
          const float sr = __int_as_float(
              __builtin_amdgcn_ds_bpermute(qq * 4, __float_as_int(scl)));
          oacc[0][r] *= sr; oacc[1][r] *= sr; oacc[2][r] *= sr; oacc[3][r] *= sr;
        }
      }
      float lsum = 0.0f;
#pragma unroll
      for (int r = 0; r < 16; ++r) {
        s0[r] = __expf(s0[r] - m_s); s1[r] = __expf(s1[r] - m_s);
        lsum += s0[r] + s1[r];
      }
      lsum += __shfl_xor(lsum, 32);
      l_s += lsum;

#define PV_STEP(KS, PP)                                                       \
      {                                                                       \
        const int rb2 = 8 * ((KS) & 1);                                       \
        const uint32_t g0a = cvt_pk_bf16(PP[rb2 + 0], PP[rb2 + 1]);           \
        const uint32_t g0b = cvt_pk_bf16(PP[rb2 + 2], PP[rb2 + 3]);           \
        const uint32_t g1a = cvt_pk_bf16(PP[rb2 + 4], PP[rb2 + 5]);           \
        const uint32_t g1b = cvt_pk_bf16(PP[rb2 + 6], PP[rb2 + 7]);           \
        const uint32_t sa = hi ? g0a : g1a, sb = hi ? g0b : g1b;              \
        const uint32_t ra = (uint32_t)__shfl_xor((int)sa, 32);                \
        const uint32_t rb_ = (uint32_t)__shfl_xor((int)sb, 32);               \
        frag_u af;                                                            \
        af.w[0] = hi ? ra  : g0a; af.w[1] = hi ? rb_ : g0b;                   \
        af.w[2] = hi ? g1a : ra;  af.w[3] = hi ? g1b : rb_;                   \
        const int gcb = 32 * (KS) + 16 * hi;                                  \
        const int vsw = (col & 7) << 4;                                       \
        _Pragma("unroll")                                                     \
        for (int db = 0; db < 4; ++db) {                                      \
          const s16x8 bv = *(const s16x8*)((const char*)Vs[cur] +             \
              (db * 32 + col) * 128 + (gcb ^ vsw));                           \
          oacc[db] = __builtin_amdgcn_mfma_f32_32x32x16_bf16(af.f, bv, oacc[db], 0, 0, 0); \
        }                                                                     \
      }
      PV_STEP(0, s0); PV_STEP(1, s0); PV_STEP(2, s1); PV_STEP(3, s1);
#undef PV_STEP
    }
    __syncthreads();
  }

  const float linv = 1.0f / l_s;
#pragma unroll
  for (int r = 0; r < 16; ++r) {
    const int qq = (r & 3) + 8 * (r >> 2) + 4 * hi;
    const float lr = __int_as_float(
        __builtin_amdgcn_ds_bpermute(qq * 4, __float_as_int(linv)));
    unsigned short* orow = ob + (size_t)(q0w + qq) * 4096 + h * 128 + col;
#pragma unroll
    for (int db = 0; db < 4; ++db)
      orow[db * 32] = f2bf(oacc[db][r] * lr);
  }
#undef STAGE_K
#undef STAGE_V
}

// ------------------------------ launch ------------------------------
extern "C" void kernel_launch(void* const* d_in, const int* in_sizes, int n_in,
                              void* d_out, int out_size, void* d_ws, size_t ws_size,
                              hipStream_t stream) {
  const float* x     = (const float*)d_in[0];
  const float* cos_f = (const float*)d_in[1];
  const float* sin_f = (const float*)d_in[2];
  const float* wq = (const float*)d_in[4];
  const float* wk = (const float*)d_in[5];
  const float* wv = (const float*)d_in[6];
  const float* wo = (const float*)d_in[7];
  float* out = (float*)d_out;

  char* ws = (char*)d_ws;
  unsigned short* xb    = (unsigned short*)(ws);                 // 2048x4096 bf16
  unsigned short* wqkvb = (unsigned short*)(ws + 16777216);      // 6144x4096 bf16
  unsigned short* wob   = (unsigned short*)(ws + 67108864);      // 4096x4096 bf16
  unsigned short* xqkvb = (unsigned short*)(ws + 100663296);     // 2048x6144 bf16
  unsigned short* qb    = (unsigned short*)(ws + 150994944);     // 2048x4096 bf16
  unsigned short* kb    = (unsigned short*)(ws + 167772160);     // 2048x1024 bf16
  unsigned short* vtb   = (unsigned short*)(ws + 171966464);     // [8*128][2048] bf16
  unsigned short* attno = (unsigned short*)(ws + 176160768);     // 2048x4096 bf16

  // all fp32->bf16 casts in one dispatch (12582912 float4 items)
  cast_all<<<dim3(49152), 256, 0, stream>>>(x, wq, wk, wv, wo, xb, wqkvb, wob);

  // fused QKV projection: [2048x4096] x [6144x4096]^T -> [2048x6144] bf16
  gemmF<64, 192, 6, 6, 1><<<dim3(512), 256, 0, stream>>>(xb, wqkvb, xqkvb, 6144);

  // fused RoPE Q+K (+fp32 cache_k write)
  rope_qk_kern<<<dim3(5120), 256, 0, stream>>>(xqkvb, cos_f, sin_f, qb,
                                               out + 8388608, kb);
  vtrans_kern<<<dim3(32, 16), 256, 0, stream>>>(xqkvb, out + 12582912, vtb);

  (void)hipMemsetAsync(out + 10485760, 0, 8388608, stream);
  (void)hipMemsetAsync(out + 14680064, 0, 8388608, stream);

  attn_fwd3<<<dim3(512), 256, 0, stream>>>(qb, kb, vtb, attno);

  // output projection: [2048x4096] x [4096x4096]^T -> d_out fp32 directly
  gemmF<64, 128, 4, 4, 0><<<dim3(512), 256, 0, stream>>>(attno, wob, out, 4096);
}

// Round 16
// 293.083 us; speedup vs baseline: 1.0260x; 1.0260x over previous
//
#include <hip/hip_runtime.h>
#include <stdint.h>

// Problem constants
#define S_LEN 2048
#define DIM_   4096
#define NH_    32
#define NKV_   8
#define HD_    128
#define QK_SCALE 0.08838834764831845f   // 1/sqrt(128)

typedef __attribute__((ext_vector_type(8)))  short  s16x8;   // 8 bf16 (4 VGPRs) MFMA frag
typedef __attribute__((ext_vector_type(4)))  float  f32x4;   // 16x16 MFMA accum
typedef __attribute__((ext_vector_type(16))) float  f32x16;  // 32x32 MFMA accum
typedef __attribute__((ext_vector_type(8))) unsigned short u16x8;
typedef __attribute__((ext_vector_type(4))) unsigned short u16x4;

union frag_u { s16x8 f; uint32_t w[4]; };

__device__ __forceinline__ unsigned short f2bf(float f) {
  union { float f; uint32_t u; } v; v.f = f;
  return (unsigned short)((v.u + 0x7fffu + ((v.u >> 16) & 1u)) >> 16);   // RNE
}

__device__ __forceinline__ float bf2f(unsigned short u) {
  union { uint32_t u; float f; } v; v.u = (uint32_t)u << 16;
  return v.f;
}

__device__ __forceinline__ uint32_t cvt_pk_bf16(float lo, float hi2) {
  uint32_t r;
  asm volatile("v_cvt_pk_bf16_f32 %0, %1, %2" : "=v"(r) : "v"(lo), "v"(hi2));
  return r;
}

// async global->LDS, 16B per lane. LDS dest is wave-uniform base + lane*16.
__device__ __forceinline__ void async_cp16(const void* g, void* l) {
  __builtin_amdgcn_global_load_lds(
      (const __attribute__((address_space(1))) unsigned int*)g,
      (__attribute__((address_space(3))) unsigned int*)l, 16, 0, 0);
}

#define WAITV(n) asm volatile("s_waitcnt vmcnt(" #n ")" ::: "memory")

// ------------- fused cast fp32 -> bf16 for all 5 inputs -------------
__global__ __launch_bounds__(256) void cast_all(
    const float* __restrict__ x,  const float* __restrict__ wq,
    const float* __restrict__ wk, const float* __restrict__ wv,
    const float* __restrict__ wo, unsigned short* __restrict__ xb,
    unsigned short* __restrict__ wqkvb, unsigned short* __restrict__ wob) {
  const int i = blockIdx.x * 256 + threadIdx.x;
  const float* src; unsigned short* dst; int off;
  if (i < 2097152)      { src = x;  dst = xb;               off = i; }
  else if (i < 6291456) { src = wq; dst = wqkvb;            off = i - 2097152; }
  else if (i < 7340032) { src = wk; dst = wqkvb + 16777216; off = i - 6291456; }
  else if (i < 8388608) { src = wv; dst = wqkvb + 20971520; off = i - 7340032; }
  else                  { src = wo; dst = wob;              off = i - 8388608; }
  const float4 v = ((const float4*)src)[off];
  u16x4 o; o[0] = f2bf(v.x); o[1] = f2bf(v.y); o[2] = f2bf(v.z); o[3] = f2bf(v.w);
  ((u16x4*)dst)[off] = o;
}

// == 128 x NTILE_N 2-phase GEMM, 4 waves x (64 x NTILE_N/2), rotate-slot ====
// R12/R13 proven skeleton (R15's LDBK1 overlap reverted: null-to-negative;
// binding constraint is phase/barrier serialization, not read-issue position).
template <int NT, int NTILE_N, int NCF, int NBCH, int BF16OUT>
__global__ __launch_bounds__(256, 2) void gemmF(
    const unsigned short* __restrict__ A, const unsigned short* __restrict__ B,
    void* __restrict__ C, int ldc) {
  constexpr int BUFB = 16384 + NTILE_N * 128;   // bytes per buffer
  __shared__ unsigned char lds[2 * BUFB];

  const int bid = blockIdx.x;
  const int idx = (bid & 7) * 64 + (bid >> 3);   // XCD-contiguous
  const int m = idx & 15, n = idx >> 4;
  const int m0 = m * 128, n0 = n * NTILE_N;

  const int tid = threadIdx.x;
  const int wave = tid >> 6, lane = tid & 63;
  const int wm = wave >> 1, wn = wave & 1;
  const int fr = lane & 15, g = lane >> 4;

  int offA[4][2], offB[NCF][2];
#pragma unroll
  for (int rf = 0; rf < 4; ++rf)
#pragma unroll
    for (int kk = 0; kk < 2; ++kk)
      offA[rf][kk] = wm * 8192 + (rf * 16 + fr) * 128 + (((kk * 4 + g + fr) & 7) << 4);
#pragma unroll
  for (int cf = 0; cf < NCF; ++cf)
#pragma unroll
    for (int kk = 0; kk < 2; ++kk)
      offB[cf][kk] = (wn * NCF * 16 + cf * 16 + fr) * 128 + (((kk * 4 + g + fr) & 7) << 4);

  const int srk = (((tid & 7) - (tid >> 3)) & 7) * 8;
  uint32_t aoff[2][2];
  uint32_t boff[NBCH];
#pragma unroll
  for (int h = 0; h < 2; ++h)
#pragma unroll
    for (int i = 0; i < 2; ++i)
      aoff[h][i] = (uint32_t)((m0 + h * 64 + i * 32 + (tid >> 3)) * 4096 + srk);
#pragma unroll
  for (int i = 0; i < NBCH; ++i)
    boff[i] = (uint32_t)((n0 + i * 32 + (tid >> 3)) * 4096 + srk);

  f32x4 acc[4][NCF] = {};
  s16x8 fa[4][2], fbk[NCF];

#define STGA(T, BUF)                                                          \
  { _Pragma("unroll") for (int h_ = 0; h_ < 2; ++h_)                          \
      _Pragma("unroll") for (int i_ = 0; i_ < 2; ++i_)                        \
        async_cp16(A + aoff[h_][i_] + (size_t)(T) * 64,                       \
                   (char*)lds + (BUF) * BUFB + h_ * 8192 + i_ * 4096 + tid * 16); }
#define STGB(T, BUF)                                                          \
  { _Pragma("unroll") for (int i_ = 0; i_ < NBCH; ++i_)                       \
      async_cp16(B + boff[i_] + (size_t)(T) * 64,                             \
                 (char*)lds + (BUF) * BUFB + 16384 + i_ * 4096 + tid * 16); }
#define LDA2(P)                                                               \
  { _Pragma("unroll") for (int rf = 0; rf < 4; ++rf)                          \
      _Pragma("unroll") for (int kk = 0; kk < 2; ++kk)                        \
        fa[rf][kk] = *(const s16x8*)((char*)lds + (P) * BUFB + offA[rf][kk]); }
#define LDBK(KK, P)                                                           \
  { _Pragma("unroll") for (int cf = 0; cf < NCF; ++cf)                        \
      fbk[cf] = *(const s16x8*)((char*)lds + (P) * BUFB + 16384 + offB[cf][KK]); }
#define BARLG()                                                               \
  __builtin_amdgcn_s_barrier();                                               \
  asm volatile("s_waitcnt lgkmcnt(0)" ::: "memory");                          \
  __builtin_amdgcn_sched_barrier(0);
#define MFK(KK)                                                               \
  __builtin_amdgcn_s_setprio(1);                                              \
  { _Pragma("unroll") for (int rf = 0; rf < 4; ++rf)                          \
      _Pragma("unroll") for (int cf = 0; cf < NCF; ++cf)                      \
        acc[rf][cf] = __builtin_amdgcn_mfma_f32_16x16x32_bf16(                \
            fa[rf][KK], fbk[cf], acc[rf][cf], 0, 0, 0); }                     \
  __builtin_amdgcn_s_setprio(0);

#define GROUPF(J, P, DO1, DO2, GATE)                                          \
  {                                                                           \
    LDA2(P); LDBK(0, P);                                                      \
    if (DO1) { STGB((J) + 1, (P) ^ 1); }                                      \
    BARLG(); MFK(0);                                                          \
    __builtin_amdgcn_s_barrier();                                             \
    LDBK(1, P);                                                               \
    if (DO2) { STGA((J) + 2, P); }                                            \
    BARLG(); MFK(1);                                                          \
    GATE;                                                                     \
    __builtin_amdgcn_s_barrier();                                             \
  }

  STGA(0, 0); STGB(0, 0); STGA(1, 1);
  WAITV(4);
  __builtin_amdgcn_s_barrier();

  for (int j = 0; j + 3 < NT; j += 2) {
    GROUPF(j, 0, true, true, WAITV(4));
    GROUPF(j + 1, 1, true, true, WAITV(4));
  }
  GROUPF(NT - 2, 0, true, false, WAITV(0));
  GROUPF(NT - 1, 1, false, false, );

#pragma unroll
  for (int rf = 0; rf < 4; ++rf)
#pragma unroll
    for (int cf = 0; cf < NCF; ++cf) {
      const size_t rbase = (size_t)(m0 + wm * 64 + rf * 16 + g * 4) * ldc
                         + (n0 + wn * NCF * 16 + cf * 16 + fr);
      if constexpr (BF16OUT) {
        unsigned short* cp = (unsigned short*)C + rbase;
#pragma unroll
        for (int r = 0; r < 4; ++r) cp[(size_t)r * ldc] = f2bf(acc[rf][cf][r]);
      } else {
        float* cp = (float*)C + rbase;
#pragma unroll
        for (int r = 0; r < 4; ++r) cp[(size_t)r * ldc] = acc[rf][cf][r];
      }
    }
#undef STGA
#undef STGB
#undef LDA2
#undef LDBK
#undef BARLG
#undef MFK
#undef GROUPF
}

// ---- fused RoPE on Q and K: bf16 xqkv -> qb/kb (+fp32 cache_k) -----
// flattened [s][5120]: c<4096 -> Q (scale folded); c>=4096 -> K.
__global__ __launch_bounds__(256) void rope_qk_kern(
    const unsigned short* __restrict__ xqkv, const float* __restrict__ cos_f,
    const float* __restrict__ sin_f, unsigned short* __restrict__ qb,
    float* __restrict__ ck, unsigned short* __restrict__ kb) {
  const int gid = blockIdx.x * 256 + threadIdx.x;   // 2048*640 threads
  const int s = gid / 640;
  const int e0 = (gid - s * 640) * 8;               // within-row elem, mult of 8
  const int i0 = (e0 & 127) >> 1;
  const float4 c  = *(const float4*)(cos_f + s * 64 + i0);
  const float4 sn = *(const float4*)(sin_f + s * 64 + i0);
  const u16x8 uv = *(const u16x8*)(xqkv + (size_t)s * 6144 + e0);
  float f[8];
#pragma unroll
  for (int j = 0; j < 8; ++j) f[j] = bf2f(uv[j]);
  const float r0 = f[0] * c.x - f[1] * sn.x, r1 = f[0] * sn.x + f[1] * c.x;
  const float r2 = f[2] * c.y - f[3] * sn.y, r3 = f[2] * sn.y + f[3] * c.y;
  const float r4 = f[4] * c.z - f[5] * sn.z, r5 = f[4] * sn.z + f[5] * c.z;
  const float r6 = f[6] * c.w - f[7] * sn.w, r7 = f[6] * sn.w + f[7] * c.w;
  if (e0 < 4096) {
    u16x8 o;
    o[0] = f2bf(r0 * QK_SCALE); o[1] = f2bf(r1 * QK_SCALE);
    o[2] = f2bf(r2 * QK_SCALE); o[3] = f2bf(r3 * QK_SCALE);
    o[4] = f2bf(r4 * QK_SCALE); o[5] = f2bf(r5 * QK_SCALE);
    o[6] = f2bf(r6 * QK_SCALE); o[7] = f2bf(r7 * QK_SCALE);
    *(u16x8*)(qb + (size_t)s * 4096 + e0) = o;
  } else {
    const int col = e0 - 4096;
    float4 o1; o1.x = r0; o1.y = r1; o1.z = r2; o1.w = r3;
    float4 o2; o2.x = r4; o2.y = r5; o2.z = r6; o2.w = r7;
    *(float4*)(ck + (size_t)s * 1024 + col) = o1;
    *(float4*)(ck + (size_t)s * 1024 + col + 4) = o2;
    u16x8 o;
    o[0] = f2bf(r0); o[1] = f2bf(r1); o[2] = f2bf(r2); o[3] = f2bf(r3);
    o[4] = f2bf(r4); o[5] = f2bf(r5); o[6] = f2bf(r6); o[7] = f2bf(r7);
    *(u16x8*)(kb + (size_t)s * 1024 + col) = o;
  }
}

// -- V: bf16 xqkv -> fp32 cache out (coalesced) + bf16 V^T [NKV*HD][S] --
__global__ __launch_bounds__(256) void vtrans_kern(
    const unsigned short* __restrict__ xqkv, float* __restrict__ cv,
    unsigned short* __restrict__ vtb) {
  __shared__ float tile[64][65];
  const int st = blockIdx.x * 64;
  const int ct = blockIdx.y * 64;
  const int tid = threadIdx.x;
#pragma unroll
  for (int j = 0; j < 16; ++j) {
    const int lin = tid + j * 256;
    const int si = lin >> 6, ci = lin & 63;
    const float v = bf2f(xqkv[(size_t)(st + si) * 6144 + 5120 + ct + ci]);
    cv[(size_t)(st + si) * 1024 + ct + ci] = v;
    tile[si][ci] = v;
  }
  __syncthreads();
#pragma unroll
  for (int j = 0; j < 16; ++j) {
    const int lin = tid + j * 256;
    const int co = lin >> 6, so = lin & 63;
    vtb[(size_t)(ct + co) * 2048 + st + so] = f2bf(tile[so][co]);
  }
}

// ---------------- flash attention v3: XCD-local KV head groups ------
// 1D grid of 512. xcd = bid&7 -> heads 4*xcd..4*xcd+3 (one hkv per XCD,
// KV slice ~1MB fits that XCD's L2). slot -> balanced causal qtile.
__global__ __launch_bounds__(256, 2) void attn_fwd3(
    const unsigned short* __restrict__ qb, const unsigned short* __restrict__ kb,
    const unsigned short* __restrict__ vtb, unsigned short* __restrict__ ob) {
  __shared__ unsigned short Ks[2][64 * 128];
  __shared__ unsigned short Vs[2][128 * 64];
  const int bid = blockIdx.x;
  const int xcd = bid & 7;
  const int rem = bid >> 3;                 // 0..63
  const int h   = xcd * 4 + (rem & 3);      // hkv = xcd
  const int slot = rem >> 2;                // 0..15
  const int hkv = h >> 2;
  const int g = (slot & 1) ? (15 - (slot >> 1)) : (slot >> 1);
  const int qtile = (h < 16) ? g : (15 - g);
  const int q0 = qtile * 128;
  const int tid = threadIdx.x, wave = tid >> 6, lane = tid & 63;
  const int col = lane & 31;
  const int hi  = lane >> 5;
  const int q0w = q0 + wave * 32;
  const int nt = (q0 >> 6) + 2;

  s16x8 qf[8];
  {
    const unsigned short* qrow = qb + (size_t)(q0w + col) * 4096 + h * 128 + hi * 8;
#pragma unroll
    for (int ks = 0; ks < 8; ++ks) qf[ks] = *(const s16x8*)(qrow + ks * 16);
  }

  f32x16 oacc[4] = {};
  float m_s = -3e30f, l_s = 0.0f;

#define STAGE_K(KT, B)                                                        \
  {                                                                           \
    const unsigned short* src = kb + (size_t)((KT) * 64) * 1024 + hkv * 128;  \
    _Pragma("unroll")                                                         \
    for (int i_ = 0; i_ < 4; ++i_) {                                          \
      const int c_ = wave * 4 + i_;                                           \
      const int row_ = c_ * 4 + (lane >> 4);                                  \
      const int cb_ = ((lane & 15) * 16) ^ ((row_ & 7) << 4);                 \
      async_cp16(src + (size_t)row_ * 1024 + (cb_ >> 1), (char*)Ks[B] + c_ * 1024); \
    }                                                                         \
  }
#define STAGE_V(KT, B)                                                        \
  {                                                                           \
    const unsigned short* src = vtb + (size_t)hkv * (128 * 2048) + (KT) * 64; \
    _Pragma("unroll")                                                         \
    for (int i_ = 0; i_ < 4; ++i_) {                                          \
      const int c_ = wave * 4 + i_;                                           \
      const int row_ = c_ * 8 + (lane >> 3);                                  \
      const int cb_ = ((lane & 7) * 16) ^ ((row_ & 7) << 4);                  \
      async_cp16(src + (size_t)row_ * 2048 + (cb_ >> 1), (char*)Vs[B] + c_ * 1024); \
    }                                                                         \
  }

  STAGE_K(0, 0); STAGE_V(0, 0);
  __syncthreads();

  for (int kt = 0; kt < nt; ++kt) {
    const int kv0 = kt * 64;
    const int cur = kt & 1;
    if (kt + 1 < nt) { STAGE_K(kt + 1, cur ^ 1); STAGE_V(kt + 1, cur ^ 1); }

    if (kv0 < q0w + 32) {
      f32x16 s0 = {}, s1 = {};
#pragma unroll
      for (int ks = 0; ks < 8; ++ks) {
        const int gcb = 32 * ks + 16 * hi;
        const int sw = (col & 7) << 4;
        const s16x8 k0 = *(const s16x8*)((const char*)Ks[cur] + col * 256 + (gcb ^ sw));
        const s16x8 k1 = *(const s16x8*)((const char*)Ks[cur] + (32 + col) * 256 + (gcb ^ sw));
        s0 = __builtin_amdgcn_mfma_f32_32x32x16_bf16(k0, qf[ks], s0, 0, 0, 0);
        s1 = __builtin_amdgcn_mfma_f32_32x32x16_bf16(k1, qf[ks], s1, 0, 0, 0);
      }

      const int qg = q0w + col;
      if (kv0 + 63 > q0w) {
#pragma unroll
        for (int r = 0; r < 16; ++r) {
          const int kvl = (r & 3) + 8 * (r >> 2) + 4 * hi;
          if (kv0 + kvl > qg)      s0[r] = -3e30f;
          if (kv0 + 32 + kvl > qg) s1[r] = -3e30f;
        }
      }

      float mxl = s0[0];
#pragma unroll
      for (int r = 1; r < 16; ++r) mxl = fmaxf(mxl, s0[r]);
#pragma unroll
      for (int r = 0; r < 16; ++r) mxl = fmaxf(mxl, s1[r]);
      const float mxf = fmaxf(mxl, __shfl_xor(mxl, 32));
      if (__any(mxf > m_s + 8.0f)) {
        const float mn = fmaxf(m_s, mxf);
        const float scl = __expf(m_s - mn);
        m_s = mn;
        l_s *= scl;
#pragma unroll
        for (int r = 0; r < 16; ++r) {
          const int qq = (r & 3) + 8 * (r >> 2) + 4 * hi;
          const float sr = __int_as_float(
              __builtin_amdgcn_ds_bpermute(qq * 4, __float_as_int(scl)));
          oacc[0][r] *= sr; oacc[1][r] *= sr; oacc[2][r] *= sr; oacc[3][r] *= sr;
        }
      }
      float lsum = 0.0f;
#pragma unroll
      for (int r = 0; r < 16; ++r) {
        s0[r] = __expf(s0[r] - m_s); s1[r] = __expf(s1[r] - m_s);
        lsum += s0[r] + s1[r];
      }
      lsum += __shfl_xor(lsum, 32);
      l_s += lsum;

#define PV_STEP(KS, PP)                                                       \
      {                                                                       \
        const int rb2 = 8 * ((KS) & 1);                                       \
        const uint32_t g0a = cvt_pk_bf16(PP[rb2 + 0], PP[rb2 + 1]);           \
        const uint32_t g0b = cvt_pk_bf16(PP[rb2 + 2], PP[rb2 + 3]);           \
        const uint32_t g1a = cvt_pk_bf16(PP[rb2 + 4], PP[rb2 + 5]);           \
        const uint32_t g1b = cvt_pk_bf16(PP[rb2 + 6], PP[rb2 + 7]);           \
        const uint32_t sa = hi ? g0a : g1a, sb = hi ? g0b : g1b;              \
        const uint32_t ra = (uint32_t)__shfl_xor((int)sa, 32);                \
        const uint32_t rb_ = (uint32_t)__shfl_xor((int)sb, 32);               \
        frag_u af;                                                            \
        af.w[0] = hi ? ra  : g0a; af.w[1] = hi ? rb_ : g0b;                   \
        af.w[2] = hi ? g1a : ra;  af.w[3] = hi ? g1b : rb_;                   \
        const int gcb = 32 * (KS) + 16 * hi;                                  \
        const int vsw = (col & 7) << 4;                                       \
        _Pragma("unroll")                                                     \
        for (int db = 0; db < 4; ++db) {                                      \
          const s16x8 bv = *(const s16x8*)((const char*)Vs[cur] +             \
              (db * 32 + col) * 128 + (gcb ^ vsw));                           \
          oacc[db] = __builtin_amdgcn_mfma_f32_32x32x16_bf16(af.f, bv, oacc[db], 0, 0, 0); \
        }                                                                     \
      }
      PV_STEP(0, s0); PV_STEP(1, s0); PV_STEP(2, s1); PV_STEP(3, s1);
#undef PV_STEP
    }
    __syncthreads();
  }

  const float linv = 1.0f / l_s;
#pragma unroll
  for (int r = 0; r < 16; ++r) {
    const int qq = (r & 3) + 8 * (r >> 2) + 4 * hi;
    const float lr = __int_as_float(
        __builtin_amdgcn_ds_bpermute(qq * 4, __float_as_int(linv)));
    unsigned short* orow = ob + (size_t)(q0w + qq) * 4096 + h * 128 + col;
#pragma unroll
    for (int db = 0; db < 4; ++db)
      orow[db * 32] = f2bf(oacc[db][r] * lr);
  }
#undef STAGE_K
#undef STAGE_V
}

// ------------------------------ launch ------------------------------
extern "C" void kernel_launch(void* const* d_in, const int* in_sizes, int n_in,
                              void* d_out, int out_size, void* d_ws, size_t ws_size,
                              hipStream_t stream) {
  const float* x     = (const float*)d_in[0];
  const float* cos_f = (const float*)d_in[1];
  const float* sin_f = (const float*)d_in[2];
  const float* wq = (const float*)d_in[4];
  const float* wk = (const float*)d_in[5];
  const float* wv = (const float*)d_in[6];
  const float* wo = (const float*)d_in[7];
  float* out = (float*)d_out;

  char* ws = (char*)d_ws;
  unsigned short* xb    = (unsigned short*)(ws);                 // 2048x4096 bf16
  unsigned short* wqkvb = (unsigned short*)(ws + 16777216);      // 6144x4096 bf16
  unsigned short* wob   = (unsigned short*)(ws + 67108864);      // 4096x4096 bf16
  unsigned short* xqkvb = (unsigned short*)(ws + 100663296);     // 2048x6144 bf16
  unsigned short* qb    = (unsigned short*)(ws + 150994944);     // 2048x4096 bf16
  unsigned short* kb    = (unsigned short*)(ws + 167772160);     // 2048x1024 bf16
  unsigned short* vtb   = (unsigned short*)(ws + 171966464);     // [8*128][2048] bf16
  unsigned short* attno = (unsigned short*)(ws + 176160768);     // 2048x4096 bf16

  // all fp32->bf16 casts in one dispatch (12582912 float4 items)
  cast_all<<<dim3(49152), 256, 0, stream>>>(x, wq, wk, wv, wo, xb, wqkvb, wob);

  // fused QKV projection: [2048x4096] x [6144x4096]^T -> [2048x6144] bf16
  gemmF<64, 192, 6, 6, 1><<<dim3(512), 256, 0, stream>>>(xb, wqkvb, xqkvb, 6144);

  // fused RoPE Q+K (+fp32 cache_k write)
  rope_qk_kern<<<dim3(5120), 256, 0, stream>>>(xqkvb, cos_f, sin_f, qb,
                                               out + 8388608, kb);
  vtrans_kern<<<dim3(32, 16), 256, 0, stream>>>(xqkvb, out + 12582912, vtb);

  (void)hipMemsetAsync(out + 10485760, 0, 8388608, stream);
  (void)hipMemsetAsync(out + 14680064, 0, 8388608, stream);

  attn_fwd3<<<dim3(512), 256, 0, stream>>>(qb, kb, vtb, attno);

  // output projection: [2048x4096] x [4096x4096]^T -> d_out fp32 directly
  gemmF<64, 128, 4, 4, 0><<<dim3(512), 256, 0, stream>>>(attno, wob, out, 4096);
}